// Round 2
// baseline (304.699 us; speedup 1.0000x reference)
//
#include <hip/hip_runtime.h>

// Reference semantics:
//   S,T,U,V = 9,9,512,512 ; H,W = 512,512 ; N = 4 ; EPS = 1e-6
//   t = flip(abs(dx*dy)) ; eps-clamp ; wgt = t/sum ; eps-clamp
//   out flat order = (H*W, 3) row-major -> out[k*3 + c]
//
// Structure (round 2):
//   kernel 1: one thread per (neighbor n, pixel k, channel c).
//     - 3 consecutive lanes cover the 3 channels of one gather -> each
//       12B gather is contiguous across lanes (3x fewer scatter txns).
//     - blockIdx mapped so XCD (bid%8 heuristic) sees exactly one
//       neighbor slice (3MB) -> L2-resident gathers.
//     - writes w*val to partial plane in d_ws.
//   kernel 2: out = sum of 4 partial planes (float4 vectorized).

#define Td 9
#define Ud 512
#define Vd 512
#define HWd (512 * 512)
#define CH3 (3 * HWd)          // 786432 floats per plane
#define EPSF 1e-6f

__global__ __launch_bounds__(256) void gather_partial(
    const float* __restrict__ data,
    const float* __restrict__ cam,
    const int* __restrict__ neighbors,
    const int* __restrict__ uv,
    float* __restrict__ partial)   // [4][CH3]
{
    // 12288 blocks total. xcd slot = bid&7; neighbor n = slot>>1 (two XCDs
    // per neighbor); pixel-block pb interleaves the slot&1 bit so every
    // (n, pb) pair is covered exactly once.
    const int bid  = blockIdx.x;
    const int slot = bid & 7;
    const int n    = slot >> 1;                      // 0..3
    const int pb   = ((bid >> 3) << 1) | (slot & 1); // 0..3071
    const int g    = pb * 256 + threadIdx.x;         // 0..786431
    const int k    = g / 3;                          // pixel index
    const int c    = g - 3 * k;                      // channel 0..2

    // ---- weights (redundant per thread; scalar/broadcast loads) ----
    const float cx = cam[0];
    const float cy = cam[1];
    float t[4];
#pragma unroll
    for (int m = 0; m < 4; ++m) {
        // flip: weight slot m comes from neighbor (3-m)'s distance product
        const float dx = cx - (float)neighbors[2 * (3 - m) + 0];
        const float dy = cy - (float)neighbors[2 * (3 - m) + 1];
        float v = fabsf(dx * dy);
        t[m] = (v <= EPSF) ? 0.0f : v;
    }
    const float tsum = t[0] + t[1] + t[2] + t[3];
    float w = t[n] / tsum;
    if (fabsf(w) <= EPSF) w = 0.0f;

    const int ns = neighbors[2 * n + 0];
    const int nt = neighbors[2 * n + 1];
    // 3 lanes share one uv entry; L1 broadcast absorbs the redundancy.
    const int2 uvv = *reinterpret_cast<const int2*>(&uv[((size_t)n * HWd + k) * 2]);
    const int off = (((ns * Td + nt) * Ud + uvv.x) * Vd + uvv.y) * 3 + c;

    partial[n * CH3 + g] = w * data[off];
}

__global__ __launch_bounds__(256) void reduce4(
    const float4* __restrict__ partial,
    float4* __restrict__ out)
{
    const int i = blockIdx.x * blockDim.x + threadIdx.x;  // 0..CH3/4-1
    const int q = CH3 / 4;
    float4 a = partial[i];
    float4 b = partial[q + i];
    float4 c = partial[2 * q + i];
    float4 d = partial[3 * q + i];
    float4 r;
    r.x = a.x + b.x + c.x + d.x;
    r.y = a.y + b.y + c.y + d.y;
    r.z = a.z + b.z + c.z + d.z;
    r.w = a.w + b.w + c.w + d.w;
    out[i] = r;
}

extern "C" void kernel_launch(void* const* d_in, const int* in_sizes, int n_in,
                              void* d_out, int out_size, void* d_ws, size_t ws_size,
                              hipStream_t stream)
{
    const float* data      = (const float*)d_in[0];
    // d_in[1] = pixel, unused (shape-only in reference)
    const float* cam       = (const float*)d_in[2];
    const int*   neighbors = (const int*)d_in[3];
    const int*   uv        = (const int*)d_in[4];
    float*       partial   = (float*)d_ws;    // 4 * CH3 * 4 B = 12 MB
    float*       out       = (float*)d_out;

    // kernel 1: 4 * CH3 threads = 3,145,728 -> 12288 blocks of 256
    gather_partial<<<12288, 256, 0, stream>>>(data, cam, neighbors, uv, partial);

    // kernel 2: CH3/4 float4s = 196608 -> 768 blocks of 256
    reduce4<<<768, 256, 0, stream>>>((const float4*)partial, (float4*)out);
}

// Round 4
// 299.696 us; speedup vs baseline: 1.0167x; 1.0167x over previous
//
#include <hip/hip_runtime.h>

// Reference semantics:
//   S,T,U,V = 9,9,512,512 ; H,W = 512,512 ; N = 4 ; EPS = 1e-6
//   t = flip(abs(dx*dy)) ; eps-clamp ; wgt = t/sum ; eps-clamp
//   out[k,c] = sum_n wgt[n] * data[ns_n, nt_n, u_n(k), v_n(k), c]
//   out flat order = (H*W, 3) row-major -> out[k*3 + c]
//
// Round 3 (re-run; prior attempt hit an infra failure, no measurement):
// single fused kernel, one thread per (pixel, channel).
//   - 3 adjacent lanes (c=0,1,2 of same pixel) gather the same 12B texel
//     -> the wave's gather coalesces ~3x vs one-thread-per-pixel scatter.
//   - no workspace, no reduce pass, one launch (round-2's partial-plane
//     path was neutral on gathers and paid ~27MB extra ws traffic).
//   - all 4 uv loads issued before any gather for memory-level parallelism.

#define Td 9
#define Ud 512
#define Vd 512
#define HWd (512 * 512)
#define CH3 (3 * HWd)
#define EPSF 1e-6f

__global__ __launch_bounds__(256) void interp_fused(
    const float* __restrict__ data,
    const float* __restrict__ cam,
    const int* __restrict__ neighbors,
    const int* __restrict__ uv,
    float* __restrict__ out)
{
    const unsigned g = blockIdx.x * 256u + threadIdx.x;  // 0..CH3-1
    const unsigned k = g / 3u;                           // pixel (magic-mul)
    const unsigned c = g - 3u * k;                       // channel 0..2

    // ---- weights (redundant per thread; scalar/broadcast loads) ----
    const float cx = cam[0];
    const float cy = cam[1];
    float t[4];
#pragma unroll
    for (int m = 0; m < 4; ++m) {
        // flip: weight slot m uses neighbor (3-m)'s distance product
        const float dx = cx - (float)neighbors[2 * (3 - m) + 0];
        const float dy = cy - (float)neighbors[2 * (3 - m) + 1];
        float v = fabsf(dx * dy);
        t[m] = (v <= EPSF) ? 0.0f : v;
    }
    const float tsum = t[0] + t[1] + t[2] + t[3];

    // ---- issue all uv loads first (MLP) ----
    int2 uvv[4];
#pragma unroll
    for (int n = 0; n < 4; ++n)
        uvv[n] = *reinterpret_cast<const int2*>(&uv[((size_t)n * HWd + k) * 2]);

    // ---- gather + accumulate ----
    float acc = 0.0f;
#pragma unroll
    for (int n = 0; n < 4; ++n) {
        float w = t[n] / tsum;
        if (fabsf(w) <= EPSF) w = 0.0f;
        const int ns = neighbors[2 * n + 0];
        const int nt = neighbors[2 * n + 1];
        const int off = (((ns * Td + nt) * Ud + uvv[n].x) * Vd + uvv[n].y) * 3 + (int)c;
        acc += w * data[off];
    }

    out[g] = acc;
}

extern "C" void kernel_launch(void* const* d_in, const int* in_sizes, int n_in,
                              void* d_out, int out_size, void* d_ws, size_t ws_size,
                              hipStream_t stream)
{
    const float* data      = (const float*)d_in[0];
    // d_in[1] = pixel, unused (shape-only in reference)
    const float* cam       = (const float*)d_in[2];
    const int*   neighbors = (const int*)d_in[3];
    const int*   uv        = (const int*)d_in[4];
    float*       out       = (float*)d_out;

    // CH3 = 786432 threads -> 3072 blocks of 256
    interp_fused<<<CH3 / 256, 256, 0, stream>>>(data, cam, neighbors, uv, out);
}